// Round 6
// baseline (123.337 us; speedup 1.0000x reference)
//
#include <hip/hip_runtime.h>
#include <hip/hip_cooperative_groups.h>

namespace cg = cooperative_groups;

#define NC 1024
#define DY 16
#define NG 65536

#define SZ_WXH (256 * 1024)        // h16 per m, [i][k] plain
#define SZ_WYA (16 * 32 * 64 * 8)  // h16 per m, A-fragment order [jt][ks][lane][jj]
#define SZ_YTB (32 * 64 * 8)       // h16 per m, B-fragment order [ks][lane][jj]

typedef float v4f __attribute__((ext_vector_type(4)));
typedef _Float16 h8 __attribute__((ext_vector_type(8)));

// Fused: stage 1 builds fragment-ordered exp tables (tensor-product trick:
// 1M exps instead of 134M) + grid output; grid.sync(); stage 2 runs the
// (WX ⊗ WY)·[Y|1] GEMM with 4 i-rows per block (WY stream halved vs r5).
__global__ __launch_bounds__(256, 4) void setconv_fused(
    const float* __restrict__ xc, const float* __restrict__ yc,
    const float* __restrict__ lsp,
    float* __restrict__ out_grid, float* __restrict__ out_z,
    _Float16* __restrict__ WXh, _Float16* __restrict__ WYA,
    _Float16* __restrict__ YTB, int m)
{
    __shared__ __align__(16) _Float16 yt_lds[SZ_YTB];   // 32 KB
    __shared__ __align__(16) _Float16 wx_lds[4][1024];  // 8 KB

    const int tid  = threadIdx.x;
    const int gtid = blockIdx.x * 256 + tid;
    const int gstr = gridDim.x * 256;

    // cheap softplus scales (rel err ~1e-6 — harmless vs 0.505 budget)
    const float l0 = 1e-5f + __logf(1.0f + __expf(lsp[0]));
    const float l1 = 1e-5f + __logf(1.0f + __expf(lsp[1]));
    const float R  = 0.84932184f;   // sqrt(log2(e)/2)
    const float s0 = R / l0, s1 = R / l1;

    // ---------------- stage 1: tables, 8 elems (16 B) per thread ----------------
    const int W1 = m * (SZ_WXH / 8);            // WXh items
    const int W2 = W1 + m * (SZ_WYA / 8);       // WYA items
    const int W3 = W2 + m * (SZ_YTB / 8);       // YTB items
    const int W4 = W3 + m * (NG / 2);           // out_grid items (2 pts each)

    for (int t = gtid; t < W4; t += gstr) {
        if (t < W1) {
            const int mm  = t >> 15;
            const int rem = t & 32767;
            const int i   = rem >> 7;
            const int k0  = (rem & 127) << 3;
            const float g = 1.0f + (float)(i - 128) * 0.015625f;
            h8 o;
#pragma unroll
            for (int jj = 0; jj < 8; ++jj) {
                const float u = (g - xc[((size_t)(mm * NC + k0 + jj)) * 2 + 0]) * s0;
                o[jj] = (_Float16)__builtin_amdgcn_exp2f(-u * u);
            }
            *(h8*)&WXh[(size_t)t * 8] = o;
        } else if (t < W2) {
            const int tt   = t - W1;
            const int mm   = tt >> 15;
            const int rem  = tt & 32767;
            const int jt   = rem >> 11;
            const int ks   = (rem >> 6) & 31;
            const int lane = rem & 63;
            const int j    = jt * 16 + (lane & 15);
            const int k0   = ks * 32 + ((lane >> 4) << 3);
            const float g  = 1.0f + (float)(j - 128) * 0.015625f;
            h8 o;
#pragma unroll
            for (int jj = 0; jj < 8; ++jj) {
                const float u = (g - xc[((size_t)(mm * NC + k0 + jj)) * 2 + 1]) * s1;
                o[jj] = (_Float16)__builtin_amdgcn_exp2f(-u * u);
            }
            *(h8*)&WYA[(size_t)tt * 8] = o;
        } else if (t < W3) {
            const int tt   = t - W2;
            const int mm   = tt >> 11;
            const int rem  = tt & 2047;
            const int lane = rem & 63;
            const int ks   = rem >> 6;
            const int ch   = lane & 15;
            const int k0   = ks * 32 + ((lane >> 4) << 3);
            h8 o;
#pragma unroll
            for (int jj = 0; jj < 8; ++jj)
                o[jj] = (_Float16)yc[(((size_t)(mm * NC + k0 + jj)) << 4) + ch];
            *(h8*)&YTB[(size_t)tt * 8] = o;
        } else {
            const int tt = t - W3;
            const int mm = tt >> 15;
            const int g  = (tt & 32767) << 1;   // even g: g and g+1 share row i
            const float gx = 1.0f + (float)((g >> 8) - 128) * 0.015625f;
            const float gy = 1.0f + (float)((g & 255) - 128) * 0.015625f;
            *(float4*)&out_grid[(((size_t)mm * NG + g)) * 2] =
                make_float4(gx, gy, gx, gy + 0.015625f);
        }
    }

    cg::this_grid().sync();

    // ---------------- stage 2: GEMM, block = 4 i × 64 j ----------------
    const int bx   = blockIdx.x;        // 0 .. m*256-1
    const int mi   = bx >> 8;
    const int rem  = bx & 255;
    const int ig   = rem >> 2;          // 0..63
    const int jg   = rem & 3;
    const int wave = tid >> 6;
    const int lane = tid & 63;
    const int q    = lane >> 4;
    const int r    = lane & 15;
    const int jt   = jg * 4 + wave;
    const int i0   = ig * 4;

    {   // stage YTB slice (32 KB) + 4 wx rows (8 KB): linear float4 copies
        const float4* src = (const float4*)(YTB + (size_t)mi * SZ_YTB);
        float4* dst = (float4*)yt_lds;
#pragma unroll
        for (int t = 0; t < 8; ++t) dst[tid + 256 * t] = src[tid + 256 * t];
        const float4* wsrc = (const float4*)(WXh + ((size_t)mi * 256 + i0) * 1024);
        float4* wdst = (float4*)wx_lds;
        wdst[tid] = wsrc[tid];
        wdst[tid + 256] = wsrc[tid + 256];
    }
    __syncthreads();

    const _Float16* wyp = WYA + ((((size_t)mi * 16 + jt) * 32) * 64 + lane) * 8;

    h8 ones;
#pragma unroll
    for (int e = 0; e < 8; ++e) ones[e] = (_Float16)1.0f;

    v4f accD[4], accS[4];
#pragma unroll
    for (int ii = 0; ii < 4; ++ii) {
        accD[ii] = (v4f){0.f, 0.f, 0.f, 0.f};
        accS[ii] = (v4f){0.f, 0.f, 0.f, 0.f};
    }

#pragma unroll 4
    for (int ks = 0; ks < 32; ++ks) {
        const h8 wy = *(const h8*)(wyp + (size_t)ks * 512);                 // coalesced dwordx4
        const h8 yt = *(const h8*)(yt_lds + ((size_t)ks * 64 + lane) * 8);  // ds_read_b128
#pragma unroll
        for (int ii = 0; ii < 4; ++ii) {
            const h8 wx = *(const h8*)(&wx_lds[ii][ks * 32 + q * 8]);       // quad-broadcast
            const h8 a  = wy * wx;                                          // 4x v_pk_mul_f16
            accD[ii] = __builtin_amdgcn_mfma_f32_16x16x32_f16(a, yt,   accD[ii], 0, 0, 0);
            accS[ii] = __builtin_amdgcn_mfma_f32_16x16x32_f16(a, ones, accS[ii], 0, 0, 0);
        }
    }

    // C/D: col(lane&15)=channel, row(q*4+reg)=j (validated r3-r5)
#pragma unroll
    for (int ii = 0; ii < 4; ++ii) {
        float* __restrict__ oz =
            out_z + ((size_t)mi * NG + (size_t)(i0 + ii) * 256 + jt * 16) * 17;
#pragma unroll
        for (int reg = 0; reg < 4; ++reg) {
            const int row = q * 4 + reg;
            oz[(size_t)row * 17 + r] = accD[ii][reg];
            if (r == 0) oz[(size_t)row * 17 + 16] = accS[ii][reg];
        }
    }
}

extern "C" void kernel_launch(void* const* d_in, const int* in_sizes, int n_in,
                              void* d_out, int out_size, void* d_ws, size_t ws_size,
                              hipStream_t stream) {
    const float* xc  = (const float*)d_in[0];   // [m, 1024, 2]
    const float* yc  = (const float*)d_in[1];   // [m, 1024, 16]
    // d_in[2] = xt — unused by the reference output
    const float* lsp = (const float*)d_in[3];   // [2]

    int m = in_sizes[0] / (NC * 2);             // = 2

    float* out_grid = (float*)d_out;
    float* out_z    = (float*)d_out + (size_t)m * NG * 2;

    _Float16* WXh = (_Float16*)d_ws;
    _Float16* WYA = WXh + (size_t)m * SZ_WXH;
    _Float16* YTB = WYA + (size_t)m * SZ_WYA;

    void* args[] = {(void*)&xc, (void*)&yc, (void*)&lsp,
                    (void*)&out_grid, (void*)&out_z,
                    (void*)&WXh, (void*)&WYA, (void*)&YTB, (void*)&m};
    dim3 grid(m * 256), block(256);
    hipLaunchCooperativeKernel((void*)setconv_fused, grid, block, args, 0, stream);
}

// Round 8
// 77.189 us; speedup vs baseline: 1.5979x; 1.5979x over previous
//
#include <hip/hip_runtime.h>

#define NC 1024
#define DY 16
#define NG 65536

typedef float v4f __attribute__((ext_vector_type(4)));
typedef _Float16 h8 __attribute__((ext_vector_type(8)));
typedef _Float16 h2 __attribute__((ext_vector_type(2)));

// Single fused kernel, no workspace, no grid sync. Tensor-product factorization:
// w(i,j,k) = wx(i,k)*wy(j,k). Block = 2 i-rows x 64 j (4 waves, one 16-j tile
// each). Per block LDS: cys (pre-scaled cy, f32), wx2 (2 rows, f16, computed
// in-block: 2048 exps), ytb (B-fragment-ordered Y^T, f16, j/i-invariant).
// Main loop: wy = 8 exps/ks (redundant 64x but only ~4us chip-wide), A-frag =
// pk_mul(wy, wx), density via ones-B MFMA on the idle matrix pipe.
__global__ __launch_bounds__(256, 4) void setconv_fused(
    const float* __restrict__ xc,   // [m, NC, 2]
    const float* __restrict__ yc,   // [m, NC, DY]
    const float* __restrict__ lsp,  // [2]
    float* __restrict__ out_grid,   // [m, 256, 256, 2]
    float* __restrict__ out_z)      // [m, 256, 256, 17]
{
    __shared__ __align__(16) _Float16 ytb[32 * 64 * 8];  // 32 KB, [ks][lane][jj]
    __shared__ __align__(16) float    cys[NC];           // 4 KB, cy * s1
    __shared__ __align__(16) _Float16 wx2[2][NC];        // 4 KB

    const int mi   = blockIdx.y;
    const int bx   = blockIdx.x;     // 0..511
    const int ig   = bx >> 2;        // 0..127
    const int jg   = bx & 3;
    const int tid  = threadIdx.x;
    const int wave = tid >> 6;
    const int lane = tid & 63;
    const int q    = lane >> 4;
    const int r    = lane & 15;
    const int jt   = jg * 4 + wave;  // 0..15
    const int i0   = ig * 2;

    const float l0 = 1e-5f + __logf(1.0f + __expf(lsp[0]));
    const float l1 = 1e-5f + __logf(1.0f + __expf(lsp[1]));
    const float R  = 0.84932184f;    // sqrt(log2(e)/2)
    const float s0 = R / l0, s1 = R / l1;

    // ---- out_grid for this block's 2x64 tile (threads 0..127, coalesced) ----
    if (tid < 128) {
        const int ii = tid >> 6, jj = tid & 63;
        const int g  = (i0 + ii) * 256 + jg * 64 + jj;
        const float gx = 1.0f + (float)((g >> 8) - 128) * 0.015625f;
        const float gy = 1.0f + (float)((g & 255) - 128) * 0.015625f;
        ((float2*)out_grid)[(size_t)mi * NG + g] = make_float2(gx, gy);
    }

    // ---- stage cys: pre-scaled y-coords of contexts ----
#pragma unroll
    for (int t = 0; t < 4; ++t) {
        const int k = tid + 256 * t;
        cys[k] = xc[(((size_t)mi * NC + k) << 1) + 1] * s1;
    }
    // ---- stage wx2: 2 rows of x-dim weights (2048 exps) ----
#pragma unroll
    for (int t = 0; t < 8; ++t) {
        const int idx = tid + 256 * t;
        const int row = idx >> 10, k = idx & 1023;
        const float gi = (1.0f + (float)(i0 + row - 128) * 0.015625f) * s0;
        const float u  = gi - xc[(((size_t)mi * NC + k) << 1)] * s0;
        wx2[row][k] = (_Float16)__builtin_amdgcn_exp2f(-u * u);
    }
    // ---- stage ytb in B-fragment order (coalesced 4x64B gathers) ----
#pragma unroll
    for (int cc = 0; cc < 8; ++cc) {
        const int cell = tid + 256 * cc;         // 0..2047 = ks*64+lane
        const int ks = cell >> 6, ln = cell & 63;
        const int ch = ln & 15;
        const int kb = ks * 32 + ((ln >> 4) << 3);
        h8 o;
#pragma unroll
        for (int jj = 0; jj < 8; ++jj)
            o[jj] = (_Float16)yc[(((size_t)mi * NC + kb + jj) << 4) + ch];
        *(h8*)&ytb[(size_t)cell * 8] = o;
    }
    __syncthreads();

    h8 ones;
#pragma unroll
    for (int e = 0; e < 8; ++e) ones[e] = (_Float16)1.0f;

    const float gyp = (1.0f + (float)(jt * 16 + r - 128) * 0.015625f) * s1;

    v4f accD0 = {0.f,0.f,0.f,0.f}, accS0 = {0.f,0.f,0.f,0.f};
    v4f accD1 = {0.f,0.f,0.f,0.f}, accS1 = {0.f,0.f,0.f,0.f};

#pragma unroll 4
    for (int ks = 0; ks < 32; ++ks) {
        const int kb = ks * 32 + q * 8;
        const float4 cya = *(const float4*)&cys[kb];      // quad-broadcast
        const float4 cyb = *(const float4*)&cys[kb + 4];
        const h8 yt  = *(const h8*)&ytb[((size_t)ks * 64 + lane) * 8];  // b128
        const h8 wxa = *(const h8*)&wx2[0][kb];           // quad-broadcast b128
        const h8 wxb = *(const h8*)&wx2[1][kb];

        const float u0 = gyp - cya.x, u1 = gyp - cya.y;
        const float u2 = gyp - cya.z, u3 = gyp - cya.w;
        const float u4 = gyp - cyb.x, u5 = gyp - cyb.y;
        const float u6 = gyp - cyb.z, u7 = gyp - cyb.w;
        const float e0 = __builtin_amdgcn_exp2f(-u0 * u0);
        const float e1 = __builtin_amdgcn_exp2f(-u1 * u1);
        const float e2 = __builtin_amdgcn_exp2f(-u2 * u2);
        const float e3 = __builtin_amdgcn_exp2f(-u3 * u3);
        const float e4 = __builtin_amdgcn_exp2f(-u4 * u4);
        const float e5 = __builtin_amdgcn_exp2f(-u5 * u5);
        const float e6 = __builtin_amdgcn_exp2f(-u6 * u6);
        const float e7 = __builtin_amdgcn_exp2f(-u7 * u7);

        union { h2 p[4]; h8 v; } wy;
        wy.p[0] = __builtin_bit_cast(h2, __builtin_amdgcn_cvt_pkrtz(e0, e1));
        wy.p[1] = __builtin_bit_cast(h2, __builtin_amdgcn_cvt_pkrtz(e2, e3));
        wy.p[2] = __builtin_bit_cast(h2, __builtin_amdgcn_cvt_pkrtz(e4, e5));
        wy.p[3] = __builtin_bit_cast(h2, __builtin_amdgcn_cvt_pkrtz(e6, e7));

        const h8 a0 = wy.v * wxa;   // v_pk_mul_f16 x4
        const h8 a1 = wy.v * wxb;
        accD0 = __builtin_amdgcn_mfma_f32_16x16x32_f16(a0, yt,   accD0, 0, 0, 0);
        accS0 = __builtin_amdgcn_mfma_f32_16x16x32_f16(a0, ones, accS0, 0, 0, 0);
        accD1 = __builtin_amdgcn_mfma_f32_16x16x32_f16(a1, yt,   accD1, 0, 0, 0);
        accS1 = __builtin_amdgcn_mfma_f32_16x16x32_f16(a1, ones, accS1, 0, 0, 0);
    }

    // C/D: col(lane&15)=channel, row(q*4+reg)=j within tile (validated r3-r6)
    float* __restrict__ oz0 =
        out_z + ((size_t)mi * NG + (size_t)i0 * 256 + jt * 16) * 17;
    float* __restrict__ oz1 = oz0 + 256 * 17;
#pragma unroll
    for (int reg = 0; reg < 4; ++reg) {
        const int row = q * 4 + reg;
        oz0[(size_t)row * 17 + r] = accD0[reg];
        oz1[(size_t)row * 17 + r] = accD1[reg];
        if (r == 0) {
            oz0[(size_t)row * 17 + 16] = accS0[reg];
            oz1[(size_t)row * 17 + 16] = accS1[reg];
        }
    }
}

extern "C" void kernel_launch(void* const* d_in, const int* in_sizes, int n_in,
                              void* d_out, int out_size, void* d_ws, size_t ws_size,
                              hipStream_t stream) {
    const float* xc  = (const float*)d_in[0];   // [m, 1024, 2]
    const float* yc  = (const float*)d_in[1];   // [m, 1024, 16]
    // d_in[2] = xt — unused by the reference output
    const float* lsp = (const float*)d_in[3];   // [2]

    const int m = in_sizes[0] / (NC * 2);       // = 2

    float* out_grid = (float*)d_out;
    float* out_z    = (float*)d_out + (size_t)m * NG * 2;

    dim3 grid(512, m), block(256);
    hipLaunchKernelGGL(setconv_fused, grid, block, 0, stream,
                       xc, yc, lsp, out_grid, out_z);
}

// Round 9
// 71.832 us; speedup vs baseline: 1.7170x; 1.0746x over previous
//
#include <hip/hip_runtime.h>

#define NC 1024
#define DY 16
#define NG 65536

#define SZ_WYA (16 * 32 * 64 * 8)  // h16 per m: [jt][ks][lane][jj] A-frag order
#define SZ_YTB (32 * 64 * 8)       // h16 per m: [ks][lane][jj]     B-frag order

typedef float v4f __attribute__((ext_vector_type(4)));
typedef _Float16 h8 __attribute__((ext_vector_type(8)));

// ---- K1: tiny table builder. 8 exps + one 16B store per thread. ----
__global__ __launch_bounds__(256) void setconv_tables(
    const float* __restrict__ xc, const float* __restrict__ yc,
    const float* __restrict__ lsp,
    _Float16* __restrict__ WYA, _Float16* __restrict__ YTB, int m)
{
    const int t  = blockIdx.x * 256 + threadIdx.x;
    const int T1 = m * (SZ_WYA / 8);
    const int T2 = T1 + m * (SZ_YTB / 8);
    if (t >= T2) return;

    if (t < T1) {
        const float l1 = 1e-5f + __logf(1.0f + __expf(lsp[1]));
        const float s1 = 0.84932184f / l1;          // sqrt(log2e/2)/l
        const int mm   = t >> 15;
        const int rem  = t & 32767;
        const int jt   = rem >> 11;
        const int ks   = (rem >> 6) & 31;
        const int lane = rem & 63;
        const int j    = jt * 16 + (lane & 15);
        const int k0   = ks * 32 + ((lane >> 4) << 3);
        const float g  = (1.0f + (float)(j - 128) * 0.015625f) * s1;
        h8 o;
#pragma unroll
        for (int jj = 0; jj < 8; ++jj) {
            const float u = g - xc[(((size_t)(mm * NC + k0 + jj)) << 1) + 1] * s1;
            o[jj] = (_Float16)__builtin_amdgcn_exp2f(-u * u);
        }
        *(h8*)&WYA[(size_t)t * 8] = o;
    } else {
        const int tt   = t - T1;
        const int mm   = tt >> 11;
        const int rem  = tt & 2047;
        const int ks   = rem >> 6;
        const int lane = rem & 63;
        const int ch   = lane & 15;
        const int k0   = ks * 32 + ((lane >> 4) << 3);
        h8 o;
#pragma unroll
        for (int jj = 0; jj < 8; ++jj)
            o[jj] = (_Float16)yc[(((size_t)(mm * NC + k0 + jj)) << 4) + ch];
        *(h8*)&YTB[(size_t)tt * 8] = o;
    }
}

// ---- K2: pure GEMM main loop (R5-proven). Block = 2 i-rows x 64 j. ----
// Per ks: wy = coalesced global dwordx4 (L2), yt = ds_read_b128,
// wx = quad-broadcast LDS (computed in prologue, off the K-loop),
// density channel via ones-B MFMA on the matrix pipe.
__global__ __launch_bounds__(256, 4) void setconv_main(
    const float* __restrict__ xc,   // [m, NC, 2]
    const float* __restrict__ lsp,  // [2]
    const _Float16* __restrict__ WYA,
    const _Float16* __restrict__ YTB,
    float* __restrict__ out_grid,   // [m, 256, 256, 2]
    float* __restrict__ out_z)      // [m, 256, 256, 17]
{
    __shared__ __align__(16) _Float16 ytb[SZ_YTB];   // 32 KB
    __shared__ __align__(16) _Float16 wx2[2][NC];    // 4 KB

    const int mi   = blockIdx.y;
    const int bx   = blockIdx.x;     // 0..511
    const int ig   = bx >> 2;        // 0..127
    const int jg   = bx & 3;
    const int tid  = threadIdx.x;
    const int wave = tid >> 6;
    const int lane = tid & 63;
    const int q    = lane >> 4;
    const int r    = lane & 15;
    const int jt   = jg * 4 + wave;  // 0..15
    const int i0   = ig * 2;

    const float l0 = 1e-5f + __logf(1.0f + __expf(lsp[0]));
    const float s0 = 0.84932184f / l0;

    // out_grid for this block's 2x64 tile (coalesced)
    if (tid < 128) {
        const int ii = tid >> 6, jj = tid & 63;
        const int g  = (i0 + ii) * 256 + jg * 64 + jj;
        const float gx = 1.0f + (float)((g >> 8) - 128) * 0.015625f;
        const float gy = 1.0f + (float)((g & 255) - 128) * 0.015625f;
        ((float2*)out_grid)[(size_t)mi * NG + g] = make_float2(gx, gy);
    }

    // prologue: wx rows (2048 exps, off the K-loop)
#pragma unroll
    for (int t = 0; t < 8; ++t) {
        const int idx = tid + 256 * t;
        const int row = idx >> 10, k = idx & 1023;
        const float gi = (1.0f + (float)(i0 + row - 128) * 0.015625f) * s0;
        const float u  = gi - xc[(((size_t)mi * NC + k) << 1)] * s0;
        wx2[row][k] = (_Float16)__builtin_amdgcn_exp2f(-u * u);
    }
    // prologue: ytb linear copy (32 KB, float4)
    {
        const float4* src = (const float4*)(YTB + (size_t)mi * SZ_YTB);
        float4* dst = (float4*)ytb;
#pragma unroll
        for (int t = 0; t < 8; ++t) dst[tid + 256 * t] = src[tid + 256 * t];
    }
    __syncthreads();

    const _Float16* wyp = WYA + (((size_t)mi * 16 + jt) * 32 * 64 + lane) * 8;

    h8 ones;
#pragma unroll
    for (int e = 0; e < 8; ++e) ones[e] = (_Float16)1.0f;

    v4f accD0 = {0.f,0.f,0.f,0.f}, accS0 = {0.f,0.f,0.f,0.f};
    v4f accD1 = {0.f,0.f,0.f,0.f}, accS1 = {0.f,0.f,0.f,0.f};

#pragma unroll 4
    for (int ks = 0; ks < 32; ++ks) {
        const h8 wy  = *(const h8*)(wyp + (size_t)ks * 512);            // global dwordx4
        const h8 yt  = *(const h8*)&ytb[((size_t)ks * 64 + lane) * 8];  // ds_read_b128
        const h8 wxa = *(const h8*)&wx2[0][ks * 32 + q * 8];            // quad-broadcast
        const h8 wxb = *(const h8*)&wx2[1][ks * 32 + q * 8];
        const h8 a0 = wy * wxa;   // 4x v_pk_mul_f16
        const h8 a1 = wy * wxb;
        accD0 = __builtin_amdgcn_mfma_f32_16x16x32_f16(a0, yt,   accD0, 0, 0, 0);
        accS0 = __builtin_amdgcn_mfma_f32_16x16x32_f16(a0, ones, accS0, 0, 0, 0);
        accD1 = __builtin_amdgcn_mfma_f32_16x16x32_f16(a1, yt,   accD1, 0, 0, 0);
        accS1 = __builtin_amdgcn_mfma_f32_16x16x32_f16(a1, ones, accS1, 0, 0, 0);
    }

    // C/D: col(lane&15)=channel, row(q*4+reg)=j (validated r3-r8);
    // per quad, 16 lanes write 64 contiguous bytes -> coalesced sectors
    float* __restrict__ oz0 =
        out_z + ((size_t)mi * NG + (size_t)i0 * 256 + jt * 16) * 17;
    float* __restrict__ oz1 = oz0 + 256 * 17;
#pragma unroll
    for (int reg = 0; reg < 4; ++reg) {
        const int row = q * 4 + reg;
        oz0[(size_t)row * 17 + r] = accD0[reg];
        oz1[(size_t)row * 17 + r] = accD1[reg];
        if (r == 0) {
            oz0[(size_t)row * 17 + 16] = accS0[reg];
            oz1[(size_t)row * 17 + 16] = accS1[reg];
        }
    }
}

extern "C" void kernel_launch(void* const* d_in, const int* in_sizes, int n_in,
                              void* d_out, int out_size, void* d_ws, size_t ws_size,
                              hipStream_t stream) {
    const float* xc  = (const float*)d_in[0];   // [m, 1024, 2]
    const float* yc  = (const float*)d_in[1];   // [m, 1024, 16]
    // d_in[2] = xt — unused by the reference output
    const float* lsp = (const float*)d_in[3];   // [2]

    int m = in_sizes[0] / (NC * 2);             // = 2

    float* out_grid = (float*)d_out;
    float* out_z    = (float*)d_out + (size_t)m * NG * 2;

    _Float16* WYA = (_Float16*)d_ws;
    _Float16* YTB = WYA + (size_t)m * SZ_WYA;

    const int total1 = m * (SZ_WYA / 8 + SZ_YTB / 8);
    hipLaunchKernelGGL(setconv_tables, dim3((total1 + 255) / 256), dim3(256),
                       0, stream, xc, yc, lsp, WYA, YTB, m);

    hipLaunchKernelGGL(setconv_main, dim3(512, m), dim3(256), 0, stream,
                       xc, lsp, WYA, YTB, out_grid, out_z);
}